// Round 7
// baseline (334.287 us; speedup 1.0000x reference)
//
#include <hip/hip_runtime.h>

// Problem constants
constexpr int BB = 8, NN = 4096, FF = 512, DD = 64, OO = 512;

using short8  = __attribute__((ext_vector_type(8))) short;
using ushort8 = __attribute__((ext_vector_type(8))) unsigned short;
using ushort4v= __attribute__((ext_vector_type(4))) unsigned short;
using uint4v  = __attribute__((ext_vector_type(4))) unsigned int;
using f32x4   = __attribute__((ext_vector_type(4))) float;
using f32x16  = __attribute__((ext_vector_type(16))) float;

__device__ __forceinline__ unsigned short f2bf(float f) {
  unsigned int u = __builtin_bit_cast(unsigned int, f);
  return (unsigned short)((u + 0x7FFFu + ((u >> 16) & 1u)) >> 16);
}

__device__ __forceinline__ f32x4 mfma16(short8 a, short8 b, f32x4 c) {
  return __builtin_amdgcn_mfma_f32_16x16x32_bf16(a, b, c, 0, 0, 0);
}
__device__ __forceinline__ f32x16 mfma32(short8 a, short8 b, f32x16 c) {
  return __builtin_amdgcn_mfma_f32_32x32x16_bf16(a, b, c, 0, 0, 0);
}

// async global->LDS, 16B per lane; lds base must be wave-uniform (lane l lands at base + l*16)
__device__ __forceinline__ void gl_lds16(const void* g, void* s) {
  __builtin_amdgcn_global_load_lds(
      (const __attribute__((address_space(1))) unsigned int*)g,
      (__attribute__((address_space(3))) unsigned int*)s,
      16, 0, 0);
}

// ---------------- kernel 1: cast x (f32) -> bf16 ----------------
__global__ void cast_x(const float* __restrict__ x, unsigned short* __restrict__ xb) {
  size_t base = ((size_t)blockIdx.x * 256 + threadIdx.x) * 8;
  float4 a = *(const float4*)(x + base);
  float4 b = *(const float4*)(x + base + 4);
  ushort8 o;
  o[0]=f2bf(a.x); o[1]=f2bf(a.y); o[2]=f2bf(a.z); o[3]=f2bf(a.w);
  o[4]=f2bf(b.x); o[5]=f2bf(b.y); o[6]=f2bf(b.z); o[7]=f2bf(b.w);
  *(ushort8*)(xb + base) = o;
}

// ---------------- kernel 2: build Wcat^T [640][512] bf16 + bias[640] ----------------
__global__ void build_w(const float* __restrict__ w1, const float* __restrict__ w2,
                        const float* __restrict__ wgt,
                        const float* __restrict__ b1, const float* __restrict__ b2,
                        unsigned short* __restrict__ Wt, float* __restrict__ bias) {
  int idx = blockIdx.x * 256 + threadIdx.x;   // 640*512 threads
  int j = idx >> 9, kk = idx & 511;
  float v = (j < 64) ? w1[kk * 64 + j]
          : (j < 128) ? w2[kk * 64 + (j - 64)]
                      : wgt[(size_t)kk * 512 + (j - 128)];
  Wt[(size_t)j * 512 + kk] = f2bf(v);
  if (kk == 0) bias[j] = (j < 64) ? b1[j] : (j < 128) ? b2[j - 64] : 0.f;
}

// ---------------- kernel 2b: compact active rows, one block per batch, no atomics ----------------
__global__ void compact_rows(const float* __restrict__ mask, int* __restrict__ cnt,
                             int* __restrict__ ridx) {
  __shared__ int wsum[4];
  __shared__ int base;
  const int b = blockIdx.x;              // 8 blocks
  const int t = threadIdx.x, lane = t & 63, w = t >> 6;
  if (t == 0) base = 0;
  __syncthreads();
  for (int it = 0; it < 16; ++it) {
    int r = it * 256 + t;
    bool act = mask[(b << 12) + r] != 0.f;
    unsigned long long bal = __ballot(act);
    int pre = __popcll(bal & ((1ull << lane) - 1ull));
    if (lane == 0) wsum[w] = __popcll(bal);
    __syncthreads();
    int woff = 0;
    for (int i = 0; i < w; ++i) woff += wsum[i];
    int tot = wsum[0] + wsum[1] + wsum[2] + wsum[3];
    if (act) ridx[(b << 12) + base + woff + pre] = r;
    __syncthreads();
    if (t == 0) base += tot;
    __syncthreads();
  }
  if (t == 0) cnt[b] = base;
}

// ---------------- kernel 2c: zero masked output rows ----------------
__global__ void zero_masked(const float* __restrict__ mask, float* __restrict__ out) {
  int gid = blockIdx.x * 256 + threadIdx.x;  // 32768*128
  int r = gid >> 7, c = (gid & 127) * 4;
  if (mask[r] == 0.f) {
    float4 z = {0.f, 0.f, 0.f, 0.f};
    *(float4*)(out + (size_t)r * 512 + c) = z;
  }
}

// ---------------- kernel 3: fused projection GEMM ----------------
// Y = Xb[32768,512] @ Wcat[512,640]; cols 0..127 -> QK row-major [32768][128],
// cols 128..639 -> supportT [8*512][4096] (transposed store).
__global__ __launch_bounds__(256, 2) void proj_gemm(
    const unsigned short* __restrict__ X, const unsigned short* __restrict__ Wt,
    const float* __restrict__ bias,
    unsigned short* __restrict__ QK, unsigned short* __restrict__ SupT) {
  __shared__ __align__(16) unsigned short Abuf[128 * 64];
  __shared__ __align__(16) unsigned short Bbuf[128 * 64];
  const int t = threadIdx.x, lane = t & 63, w = t >> 6;
  const int nblk = blockIdx.x;           // 0..4
  const int m0 = blockIdx.y * 128, n0 = nblk * 128;
  const int wm = w & 1, wn = w >> 1;

  f32x4 acc[4][4] = {};
  for (int kt = 0; kt < 8; ++kt) {
    for (int i = 0; i < 4; ++i) {
      int c = i * 4 + w;
      int row = c * 8 + (lane >> 3);
      int k0 = (lane & 7) * 8;
      gl_lds16(X + (size_t)(m0 + row) * 512 + kt * 64 + k0, &Abuf[c * 512]);
      gl_lds16(Wt + (size_t)(n0 + row) * 512 + kt * 64 + k0, &Bbuf[c * 512]);
    }
    __syncthreads();
    short8 af[4][2], bfr[4][2];
    for (int mi = 0; mi < 4; ++mi)
      for (int kc = 0; kc < 2; ++kc) {
        int row = wm * 64 + mi * 16 + (lane & 15);
        int d = kc * 32 + (lane >> 4) * 8;
        af[mi][kc] = *(const short8*)&Abuf[row * 64 + d];
      }
    for (int ni = 0; ni < 4; ++ni)
      for (int kc = 0; kc < 2; ++kc) {
        int col = wn * 64 + ni * 16 + (lane & 15);
        int d = kc * 32 + (lane >> 4) * 8;
        bfr[ni][kc] = *(const short8*)&Bbuf[col * 64 + d];
      }
    for (int mi = 0; mi < 4; ++mi)
      for (int ni = 0; ni < 4; ++ni)
        for (int kc = 0; kc < 2; ++kc)
          acc[mi][ni] = mfma16(af[mi][kc], bfr[ni][kc], acc[mi][ni]);
    __syncthreads();
  }
  for (int mi = 0; mi < 4; ++mi)
    for (int ni = 0; ni < 4; ++ni) {
      int col_g = n0 + wn * 64 + ni * 16 + (lane & 15);
      int row0 = m0 + wm * 64 + mi * 16 + ((lane >> 4) * 4);
      float bv = bias[col_g];
      if (nblk == 0) {
        for (int j = 0; j < 4; ++j)
          QK[(size_t)(row0 + j) * 128 + col_g] = f2bf(acc[mi][ni][j] + bv);
      } else {
        int scol = col_g - 128;
        int b = row0 >> 12, rl = row0 & 4095;
        ushort4v pk;
        for (int j = 0; j < 4; ++j) pk[j] = f2bf(acc[mi][ni][j] + bv);
        *(ushort4v*)&SupT[(size_t)(b * 512 + scol) * 4096 + rl] = pk;
      }
    }
}

// ---------------- kernel 4: fused attention, in-register P (swapped QK^T), 1 barrier/iter ----
// Block: 64 active rows x 256 cols (colh), 8 waves = 2 row-halves x 4 col-groups.
// Each wave owns 32 rows x 64 cols. S^T = mfma32(K, Q) makes P lane-local
// (D: col=lane&31=qrow, row=(reg&3)+8*(reg>>2)+4*(lane>>5)=key); exp in-register,
// cvt_pk + shfl_xor(32) reassembles the PV A-fragment (row=lane&31, k=(lane>>5)*8+j)
// -> NO P LDS, NO softmax barrier. Single barrier per K-tile for the K/V double
// buffer; stage(kt+1) issued after the barrier (race-free as in R6). Unnormalized
// exp is safe (logits tiny by construction); divide by l in the epilogue.
__global__ __launch_bounds__(512, 4) void attn_kernel(
    const unsigned short* __restrict__ QK, const unsigned short* __restrict__ SupT,
    const int* __restrict__ cnt, const int* __restrict__ ridx,
    float* __restrict__ out) {
  __shared__ __align__(16) unsigned short Kb[2][32 * 64];   // xor-swizzled blocks (8KB)
  __shared__ __align__(16) unsigned short Vt[2][256 * 32];  // [colL][key], xor-swizzled (32KB)
  __shared__ float lsh2[2][32];
  __shared__ int rsh[64];

  // batch in low bits -> one batch per XCD (L2 affinity)
  const int batch = blockIdx.x & 7;
  const int rest  = blockIdx.x >> 3;       // 0..127
  const int chunk = rest >> 1, colh = rest & 1;
  const int n_act = cnt[batch];
  if (chunk * 64 >= n_act) return;
  const int rem = min(64, n_act - chunk * 64);

  const int t = threadIdx.x, lane = t & 63, w = t >> 6;
  const int keybase = batch << 12;
  const int wm = w >> 2;                 // row half (0,1): rows wm*32..+31
  const int wo = w & 3;                  // col group: cols wo*64..+63 (within 256)
  const int l31 = lane & 31, g = lane >> 5;

  if (t < 64) rsh[t] = ridx[(batch << 12) + chunk * 64 + min(t, rem - 1)];
  __syncthreads();

  // Q B-fragments for mfma32: col=qrow=lane&31, k(d) = dblk*16 + g*8 + j
  short8 qf[4];
  {
    int rl = rsh[wm * 32 + l31];
    const unsigned short* qp = QK + (size_t)(keybase + rl) * 128 + g * 8;
    qf[0] = *(const short8*)(qp);
    qf[1] = *(const short8*)(qp + 16);
    qf[2] = *(const short8*)(qp + 32);
    qf[3] = *(const short8*)(qp + 48);
  }

  f32x16 accA = {}, accB = {};
  float lacc = 0.f;

  auto stage = [&](int p, int key0) {
    if (w < 4) {  // K tile: 32 keys x 64 d (1 instr, waves 0-3), source-swizzled
      int key = w * 8 + (lane >> 3);
      int q = lane & 7;
      int d0 = (q ^ (key & 7)) * 8;
      gl_lds16(QK + (size_t)(keybase + key0 + key) * 128 + 64 + d0, &Kb[p][w * 512]);
    }
    for (int i = 0; i < 2; ++i) {  // Vt tile: 256 cols x 32 keys (2 instr/wave)
      int c = i * 8 + w;                     // 0..15 local col-block
      int colL = c * 16 + (lane >> 2);       // local col 0..255
      int q = lane & 3;
      int k0 = (q ^ ((colL >> 1) & 3)) * 8;
      gl_lds16(SupT + (size_t)(batch * 512 + colh * 256 + colL) * 4096 + key0 + k0,
               &Vt[p][c * 512]);
    }
  };

  stage(0, 0);
  for (int kt = 0; kt < 128; ++kt) {
    const int p = kt & 1;
    asm volatile("s_waitcnt vmcnt(0)" ::: "memory");
    asm volatile("s_barrier" ::: "memory");            // tile kt ready
    if (kt < 127) stage(p ^ 1, (kt + 1) * 32);         // race-free: after barrier

    // S^T phase: mfma32(K, Q) over d=64 (4 chained mfma, k=16 each)
    f32x16 st = {};
    __builtin_amdgcn_s_setprio(1);
#pragma unroll
    for (int d = 0; d < 4; ++d) {
      short8 kf = *(const short8*)&Kb[p][l31 * 64 + (((d << 1) + g) ^ (l31 & 7)) * 8];
      st = mfma32(kf, qf[d], st);
    }
    __builtin_amdgcn_s_setprio(0);

    // exp (unnormalized) + denominator accumulate + pack to bf16 pairs
    float pv[16];
#pragma unroll
    for (int r = 0; r < 16; ++r) { pv[r] = __expf(st[r] * 0.125f); lacc += pv[r]; }
    unsigned wpk[8];
#pragma unroll
    for (int i = 0; i < 8; ++i) {
      unsigned u;
      asm("v_cvt_pk_bf16_f32 %0, %1, %2" : "=v"(u) : "v"(pv[2 * i]), "v"(pv[2 * i + 1]));
      wpk[i] = u;
    }
    // lane l key-groups: own keys (reg&3)+8*(reg>>2)+4g; partner (l^32) holds the
    // complementary 4-key groups. 4 shfl slots carry what the OTHER half needs.
    unsigned r0 = (unsigned)__shfl_xor((int)(g ? wpk[0] : wpk[2]), 32);
    unsigned r1 = (unsigned)__shfl_xor((int)(g ? wpk[1] : wpk[3]), 32);
    unsigned r2 = (unsigned)__shfl_xor((int)(g ? wpk[4] : wpk[6]), 32);
    unsigned r3 = (unsigned)__shfl_xor((int)(g ? wpk[5] : wpk[7]), 32);
    uint4v a0v = g ? (uint4v){r0, r1, wpk[2], wpk[3]} : (uint4v){wpk[0], wpk[1], r0, r1};
    uint4v a1v = g ? (uint4v){r2, r3, wpk[6], wpk[7]} : (uint4v){wpk[4], wpk[5], r2, r3};
    short8 pa0 = __builtin_bit_cast(short8, a0v);   // A-frag keys 0-15
    short8 pa1 = __builtin_bit_cast(short8, a1v);   // A-frag keys 16-31

    // PV phase: out[32 rows][64 cols] via 4 mfma32 (2 col-groups x 2 key-halves)
    {
      int colL = wo * 64 + l31;
      int sw = (colL >> 1) & 3;                       // same for colL and colL+32
      const unsigned short* vb0 = &Vt[p][colL * 32];
      const unsigned short* vb1 = vb0 + 32 * 32;
      short8 v00 = *(const short8*)(vb0 + ((g ^ sw) << 3));
      short8 v01 = *(const short8*)(vb0 + (((2 + g) ^ sw) << 3));
      short8 v10 = *(const short8*)(vb1 + ((g ^ sw) << 3));
      short8 v11 = *(const short8*)(vb1 + (((2 + g) ^ sw) << 3));
      __builtin_amdgcn_s_setprio(1);
      accA = mfma32(pa0, v00, accA);
      accA = mfma32(pa1, v01, accA);
      accB = mfma32(pa0, v10, accB);
      accB = mfma32(pa1, v11, accB);
      __builtin_amdgcn_s_setprio(0);
    }
  }

  // denominator: lanes l and l^32 hold complementary key-halves for qrow l&31
  float ltot = lacc + __shfl_xor(lacc, 32);
  if (wo == 0 && lane < 32) lsh2[wm][lane] = 1.f / ltot;
  __syncthreads();

#pragma unroll
  for (int reg = 0; reg < 16; ++reg) {
    int qrow = (reg & 3) + 8 * (reg >> 2) + 4 * g;
    int slot = wm * 32 + qrow;
    if (slot < rem) {
      float linv = lsh2[wm][qrow];
      int rl = rsh[slot];
      float* op = out + (size_t)(keybase + rl) * 512 + colh * 256 + wo * 64 + l31;
      op[0]  = accA[reg] * linv;
      op[32] = accB[reg] * linv;
    }
  }
}

extern "C" void kernel_launch(void* const* d_in, const int* in_sizes, int n_in,
                              void* d_out, int out_size, void* d_ws, size_t ws_size,
                              hipStream_t stream) {
  const float* x    = (const float*)d_in[0];
  const float* mask = (const float*)d_in[1];
  const float* w1   = (const float*)d_in[2];
  const float* b1   = (const float*)d_in[3];
  const float* w2   = (const float*)d_in[4];
  const float* b2   = (const float*)d_in[5];
  const float* wgt  = (const float*)d_in[6];
  float* out = (float*)d_out;

  char* ws = (char*)d_ws;
  unsigned short* Xb   = (unsigned short*)(ws);               // 33,554,432 B
  unsigned short* QK   = (unsigned short*)(ws + 33554432);    //  8,388,608 B
  unsigned short* SupT = (unsigned short*)(ws + 41943040);    // 33,554,432 B
  unsigned short* Wt   = (unsigned short*)(ws + 75497472);    //    655,360 B
  float* bias          = (float*)(ws + 76152832);             //      2,560 B
  int*   cnt           = (int*)(ws + 76417536);               //         32 B
  int*   ridx          = (int*)(ws + 76417664);               //    131,072 B

  build_w<<<dim3(1280), dim3(256), 0, stream>>>(w1, w2, wgt, b1, b2, Wt, bias);
  compact_rows<<<dim3(8), dim3(256), 0, stream>>>(mask, cnt, ridx);
  cast_x<<<dim3(8192), dim3(256), 0, stream>>>(x, Xb);
  proj_gemm<<<dim3(5, 256), dim3(256), 0, stream>>>(Xb, Wt, bias, QK, SupT);
  attn_kernel<<<dim3(1024), dim3(512), 0, stream>>>(QK, SupT, cnt, ridx, out);
  zero_masked<<<dim3(16384), dim3(256), 0, stream>>>(mask, out);
}